// Round 3
// baseline (876.892 us; speedup 1.0000x reference)
//
#include <hip/hip_runtime.h>

// ---------------------------------------------------------------------------
// TwoBranchFork: out = LN( concat(x@q(w_a)^T, x@q(w_b)^T) @ w_proj^T )
// Reassociated: W_eff = w_proj @ [q(w_a); q(w_b)]  (4096x4096), h = x @ W_eff^T
// Round 3: read-ahead register pipelining. Every ds_read issues one region
// before its consuming MFMA (loop-carried a0/b01 across the backedge); 3
// barriers/tile; counted vmcnt(4); stages placed >=1 barrier after the
// consuming MFMA of the rows they overwrite:
//   R1: [read b23(t) | stage A0(t+1)->sA[p^1] | MFMA Q1(mh0,n01) | bar]
//   R2: [read a1(t)  | stage A1(t+1)->sA[p^1] | MFMA Q2(mh0,n23) | bar]
//   R3: [stage B0(t+2)->sB[p] | MFMA Q3(mh1,n23) | stage B1(t+2) |
//        MFMA Q4(mh1,n01) | vmcnt(4) | bar | read a0,b01(t+1)]
// Ledger: A(t+1) stage overwrites A(t-1): a1(t-1) consumed at t-1 Q3 (before
// t-1 R3 bar) ✓. B(t+2) stage overwrites B(t): b01(t) consumed t Q1 (< R1
// bar), b23(t) consumed t Q2 (< R2 bar) ✓. vmcnt(4) leaves only B(t+2)'s 4
// loads -> A(t+1),B(t+1) landed before trailing reads ✓.
// ---------------------------------------------------------------------------

typedef unsigned int u32;
typedef unsigned short u16;
typedef __bf16 bf16x8 __attribute__((ext_vector_type(8)));
typedef float f32x4 __attribute__((ext_vector_type(4)));
typedef u16 u16x8 __attribute__((ext_vector_type(8)));

#define AS1 __attribute__((address_space(1)))
#define AS3 __attribute__((address_space(3)))
#define FENCE() asm volatile("" ::: "memory")

__device__ __forceinline__ u16 f2bf(float f) {
  u32 u = __float_as_uint(f);
  u32 r = (u + 0x7fffu + ((u >> 16) & 1u)) >> 16;  // RNE
  return (u16)r;
}

// fp8 e4m3fn quantize-dequantize via HW cvt (OCP format + RNE on gfx950)
__device__ __forceinline__ float q_e4m3(float v) {
  int p = __builtin_amdgcn_cvt_pk_fp8_f32(v, v, 0, false);
  return __builtin_amdgcn_cvt_f32_fp8(p, 0);
}

__device__ __forceinline__ void gload16(const void* g, void* l) {
  __builtin_amdgcn_global_load_lds((const AS1 u32*)g, (AS3 u32*)l, 16, 0, 0);
}

// ---------------- elementwise f32 -> bf16 ----------------
__global__ __launch_bounds__(256) void k_f32_to_bf16(
    const float* __restrict__ in, u16* __restrict__ out, long n) {
  long i0 = ((long)blockIdx.x * 256 + threadIdx.x) * 8;
  long stride = (long)gridDim.x * 256 * 8;
  for (long i = i0; i < n; i += stride) {
    float4 a = *(const float4*)(in + i);
    float4 b = *(const float4*)(in + i + 4);
    u16x8 o;
    o[0] = f2bf(a.x); o[1] = f2bf(a.y); o[2] = f2bf(a.z); o[3] = f2bf(a.w);
    o[4] = f2bf(b.x); o[5] = f2bf(b.y); o[6] = f2bf(b.z); o[7] = f2bf(b.w);
    *(u16x8*)(out + i) = o;
  }
}

// ---------------- quantize (fp8 rt) + transpose into wqT ----------------
__global__ __launch_bounds__(256) void k_quant_transpose(
    const float* __restrict__ w, const float* __restrict__ s,
    u16* __restrict__ oT, int J, int Kd, int sCols, long oStride, int oColOff) {
  __shared__ u16 tile[64][72];
  int j0 = blockIdx.x * 64;
  int k0 = blockIdx.y * 64;
  float sc = s[(j0 >> 7) * sCols + (k0 >> 7)];
  int t = threadIdx.x;
  int row = t >> 2, seg = t & 3;
  const float4* src = (const float4*)(w + (long)(j0 + row) * Kd + k0 + seg * 16);
  u16* dst = &tile[row][seg * 16];
#pragma unroll
  for (int ii = 0; ii < 4; ++ii) {
    float4 v = src[ii];
    dst[ii * 4 + 0] = f2bf(q_e4m3(v.x / sc) * sc);
    dst[ii * 4 + 1] = f2bf(q_e4m3(v.y / sc) * sc);
    dst[ii * 4 + 2] = f2bf(q_e4m3(v.z / sc) * sc);
    dst[ii * 4 + 3] = f2bf(q_e4m3(v.w / sc) * sc);
  }
  __syncthreads();
  int r = t >> 2, cs = t & 3;
  u16* op = oT + (long)(k0 + r) * oStride + oColOff + j0 + cs * 16;
  u16x8 o0, o1;
#pragma unroll
  for (int ii = 0; ii < 8; ++ii) o0[ii] = tile[cs * 16 + ii][r];
#pragma unroll
  for (int ii = 0; ii < 8; ++ii) o1[ii] = tile[cs * 16 + 8 + ii][r];
  *(u16x8*)op = o0;
  *(u16x8*)(op + 8) = o1;
}

// ---------------- 256x256 read-ahead bf16 bt-GEMM: C = A[M,K] * B[N,K]^T ----
template <bool OUT_BF16>
__global__ __launch_bounds__(512, 2) void k_gemm8(
    const u16* __restrict__ A, const u16* __restrict__ B, void* __restrict__ Cv,
    int M, int N, int K) {
  __shared__ u16 sA[2][256 * 64];
  __shared__ u16 sB[2][256 * 64];

  const int tid = threadIdx.x;
  const int lane = tid & 63;
  const int wave = tid >> 6;
  const int wr = wave >> 2, wc = wave & 3;  // 2x4 wave grid, each 128x64 of C

  // T1: XCD-aware block swizzle (grid % 8 == 0 by construction)
  const int nwg = gridDim.x;
  const int wg = blockIdx.x;
  const int wgs = (wg & 7) * (nwg >> 3) + (wg >> 3);
  const int nbn = N >> 8;
  const int m0 = (wgs / nbn) << 8;
  const int n0 = (wgs % nbn) << 8;
  const int NT = K >> 6;

  const int lrow = lane & 15;
  const int kslot = lane >> 4;       // 0..3: 8-elem k-slot within 64-col row
  const int st_row = lane >> 3;      // staging: row within the 8-row stripe
  const int st_slot = lane & 7;
  const int st_src = ((st_slot ^ st_row) * 8);  // T2 inverse-swizzled source

  f32x4 acc[8][4] = {};

  auto stage = [&](const u16* __restrict__ G, int row0, u16* lds, int half,
                   int kt) {
#pragma unroll
    for (int r = 0; r < 2; ++r) {
      int row = half * 128 + r * 64 + wave * 8 + st_row;
      const u16* g = G + (long)(row0 + row) * K + kt * 64 + st_src;
      u16* l = lds + row * 64 + st_slot * 8;
      gload16(g, l);
    }
  };
  // T2 swizzled LDS fragment reads (2-way max bank aliasing = free)
  auto ldA = [&](const u16* sa, int mh, int m, int ks) -> bf16x8 {
    int row = wr * 128 + mh * 64 + m * 16 + lrow;
    int slot = (ks * 4 + kslot) ^ (row & 7);
    return *(const bf16x8*)(sa + row * 64 + slot * 8);
  };
  auto ldB = [&](const u16* sb, int n, int ks) -> bf16x8 {
    int row = wc * 64 + n * 16 + lrow;
    int slot = (ks * 4 + kslot) ^ (row & 7);
    return *(const bf16x8*)(sb + row * 64 + slot * 8);
  };

  // ---- prologue: A(0),B(0),B(1) staged; wait A(0),B(0); preload a0/b01(0)
  stage(A, m0, sA[0], 0, 0);
  stage(A, m0, sA[0], 1, 0);
  stage(B, n0, sB[0], 0, 0);
  stage(B, n0, sB[0], 1, 0);
  if (NT > 1) {
    stage(B, n0, sB[1], 0, 1);
    stage(B, n0, sB[1], 1, 1);
    asm volatile("s_waitcnt vmcnt(4)" ::: "memory");
  } else {
    asm volatile("s_waitcnt vmcnt(0)" ::: "memory");
  }
  __builtin_amdgcn_s_barrier();
  FENCE();

  bf16x8 a0[4][2], b01[2][2];  // loop-carried: tile-t operands for Q1/Q4
#pragma unroll
  for (int m = 0; m < 4; ++m)
#pragma unroll
    for (int ks = 0; ks < 2; ++ks) a0[m][ks] = ldA(sA[0], 0, m, ks);
#pragma unroll
  for (int n = 0; n < 2; ++n)
#pragma unroll
    for (int ks = 0; ks < 2; ++ks) b01[n][ks] = ldB(sB[0], n, ks);

  for (int t = 0; t < NT; ++t) {
    const int p = t & 1;
    const u16* sa = sA[p];
    const u16* sb = sB[p];
    u16* saN = sA[p ^ 1];
    u16* sbC = sB[p];  // B(t+2) has same parity
    bf16x8 a1[4][2], b23[2][2];

    // ---- R1: read b23(t) | stage A0(t+1) | MFMA Q1(mh0,n01) | bar
#pragma unroll
    for (int n = 0; n < 2; ++n)
#pragma unroll
      for (int ks = 0; ks < 2; ++ks) b23[n][ks] = ldB(sb, n + 2, ks);
    if (t + 1 < NT) stage(A, m0, saN, 0, t + 1);
    __builtin_amdgcn_s_setprio(1);
#pragma unroll
    for (int m = 0; m < 4; ++m)
#pragma unroll
      for (int n = 0; n < 2; ++n)
#pragma unroll
        for (int ks = 0; ks < 2; ++ks)
          acc[m][n] = __builtin_amdgcn_mfma_f32_16x16x32_bf16(
              a0[m][ks], b01[n][ks], acc[m][n], 0, 0, 0);
    __builtin_amdgcn_s_setprio(0);
    FENCE();
    __builtin_amdgcn_s_barrier();
    FENCE();

    // ---- R2: read a1(t) | stage A1(t+1) | MFMA Q2(mh0,n23) | bar
#pragma unroll
    for (int m = 0; m < 4; ++m)
#pragma unroll
      for (int ks = 0; ks < 2; ++ks) a1[m][ks] = ldA(sa, 1, m, ks);
    if (t + 1 < NT) stage(A, m0, saN, 1, t + 1);
    __builtin_amdgcn_s_setprio(1);
#pragma unroll
    for (int m = 0; m < 4; ++m)
#pragma unroll
      for (int n = 2; n < 4; ++n)
#pragma unroll
        for (int ks = 0; ks < 2; ++ks)
          acc[m][n] = __builtin_amdgcn_mfma_f32_16x16x32_bf16(
              a0[m][ks], b23[n - 2][ks], acc[m][n], 0, 0, 0);
    __builtin_amdgcn_s_setprio(0);
    FENCE();
    __builtin_amdgcn_s_barrier();
    FENCE();

    // ---- R3: stage B0(t+2) | Q3(mh1,n23) | stage B1(t+2) | Q4(mh1,n01)
    //          | vmcnt(4) | bar | read a0,b01(t+1)
    if (t + 2 < NT) stage(B, n0, sbC, 0, t + 2);
    __builtin_amdgcn_s_setprio(1);
#pragma unroll
    for (int m = 0; m < 4; ++m)
#pragma unroll
      for (int n = 2; n < 4; ++n)
#pragma unroll
        for (int ks = 0; ks < 2; ++ks)
          acc[4 + m][n] = __builtin_amdgcn_mfma_f32_16x16x32_bf16(
              a1[m][ks], b23[n - 2][ks], acc[4 + m][n], 0, 0, 0);
    __builtin_amdgcn_s_setprio(0);
    if (t + 2 < NT) stage(B, n0, sbC, 1, t + 2);
    __builtin_amdgcn_s_setprio(1);
#pragma unroll
    for (int m = 0; m < 4; ++m)
#pragma unroll
      for (int n = 0; n < 2; ++n)
#pragma unroll
        for (int ks = 0; ks < 2; ++ks)
          acc[4 + m][n] = __builtin_amdgcn_mfma_f32_16x16x32_bf16(
              a1[m][ks], b01[n][ks], acc[4 + m][n], 0, 0, 0);
    __builtin_amdgcn_s_setprio(0);
    FENCE();
    if (t + 2 < NT)
      asm volatile("s_waitcnt vmcnt(4)" ::: "memory");
    else
      asm volatile("s_waitcnt vmcnt(0)" ::: "memory");
    __builtin_amdgcn_s_barrier();
    FENCE();
    if (t + 1 < NT) {
      const u16* sa2 = sA[p ^ 1];
      const u16* sb2 = sB[p ^ 1];
#pragma unroll
      for (int m = 0; m < 4; ++m)
#pragma unroll
        for (int ks = 0; ks < 2; ++ks) a0[m][ks] = ldA(sa2, 0, m, ks);
#pragma unroll
      for (int n = 0; n < 2; ++n)
#pragma unroll
        for (int ks = 0; ks < 2; ++ks) b01[n][ks] = ldB(sb2, n, ks);
    }
  }

  // ---- epilogue: C/D layout col=lane&15, row=(lane>>4)*4+reg (m89-verified)
  const int rb = m0 + wr * 128 + (lane >> 4) * 4;
  const int cb = n0 + wc * 64 + lrow;
#pragma unroll
  for (int mf = 0; mf < 8; ++mf) {
#pragma unroll
    for (int r = 0; r < 4; ++r) {
      const long rowoff = (long)(rb + mf * 16 + r) * N + cb;
#pragma unroll
      for (int n = 0; n < 4; ++n) {
        if (OUT_BF16)
          ((u16*)Cv)[rowoff + n * 16] = f2bf(acc[mf][n][r]);
        else
          ((float*)Cv)[rowoff + n * 16] = acc[mf][n][r];
      }
    }
  }
}

// ---------------- in-place LayerNorm over rows of 4096 ----------------
__global__ __launch_bounds__(256) void k_layernorm(
    float* __restrict__ h, const float* __restrict__ gamma,
    const float* __restrict__ beta) {
  const int H = 4096;
  float* p = h + (long)blockIdx.x * H;
  int t = threadIdx.x;
  float4 v[4];
  float sum = 0.f, sq = 0.f;
#pragma unroll
  for (int i = 0; i < 4; ++i) {
    v[i] = ((const float4*)p)[i * 256 + t];
    sum += v[i].x + v[i].y + v[i].z + v[i].w;
    sq += v[i].x * v[i].x + v[i].y * v[i].y + v[i].z * v[i].z + v[i].w * v[i].w;
  }
#pragma unroll
  for (int off = 32; off > 0; off >>= 1) {
    sum += __shfl_down(sum, off, 64);
    sq += __shfl_down(sq, off, 64);
  }
  __shared__ float ss[4], sg[4];
  if ((t & 63) == 0) { ss[t >> 6] = sum; sg[t >> 6] = sq; }
  __syncthreads();
  sum = ss[0] + ss[1] + ss[2] + ss[3];
  sq = sg[0] + sg[1] + sg[2] + sg[3];
  float mu = sum * (1.0f / H);
  float var = sq * (1.0f / H) - mu * mu;
  float rs = rsqrtf(var + 1e-5f);
#pragma unroll
  for (int i = 0; i < 4; ++i) {
    float4 g = ((const float4*)gamma)[i * 256 + t];
    float4 b = ((const float4*)beta)[i * 256 + t];
    float4 o;
    o.x = (v[i].x - mu) * rs * g.x + b.x;
    o.y = (v[i].y - mu) * rs * g.y + b.y;
    o.z = (v[i].z - mu) * rs * g.z + b.z;
    o.w = (v[i].w - mu) * rs * g.w + b.w;
    ((float4*)p)[i * 256 + t] = o;
  }
}

extern "C" void kernel_launch(void* const* d_in, const int* in_sizes, int n_in,
                              void* d_out, int out_size, void* d_ws,
                              size_t ws_size, hipStream_t stream) {
  const float* x      = (const float*)d_in[0];
  const float* w_a    = (const float*)d_in[1];
  const float* s_a    = (const float*)d_in[2];
  const float* w_b    = (const float*)d_in[3];
  const float* s_b    = (const float*)d_in[4];
  const float* w_proj = (const float*)d_in[5];
  const float* gamma  = (const float*)d_in[6];
  const float* beta   = (const float*)d_in[7];

  const int H = 4096, LO = 8192, SO = 2048, NR = 8192;
  const int KT = LO + SO;  // 10240

  char* ws = (char*)d_ws;
  u16* xb   = (u16*)(ws);                 // 64 MiB
  u16* wpb  = (u16*)(ws + 0x4000000L);    // 80 MiB
  u16* wqT  = (u16*)(ws + 0x9000000L);    // 80 MiB
  u16* weff = (u16*)(ws + 0xE000000L);    // 32 MiB
  float* h  = (float*)d_out;

  // 1. converts
  k_f32_to_bf16<<<2048, 256, 0, stream>>>(x, xb, (long)NR * H);
  k_f32_to_bf16<<<2048, 256, 0, stream>>>(w_proj, wpb, (long)H * KT);

  // 2. quantize + transpose weights into wqT [H x (LO+SO)]
  k_quant_transpose<<<dim3(LO / 64, H / 64), 256, 0, stream>>>(
      w_a, s_a, wqT, LO, H, H / 128, (long)KT, 0);
  k_quant_transpose<<<dim3(SO / 64, H / 64), 256, 0, stream>>>(
      w_b, s_b, wqT, SO, H, H / 128, (long)KT, LO);

  // 3. W_eff = w_proj @ Wq  -> bf16 [H][H]
  k_gemm8<true><<<(H / 256) * (H / 256), 512, 0, stream>>>(
      wpb, wqT, (void*)weff, H, H, KT);

  // 4. h = x @ W_eff^T  -> fp32 into d_out
  k_gemm8<false><<<(NR / 256) * (H / 256), 512, 0, stream>>>(
      xb, weff, (void*)h, NR, H, H);

  // 5. LayerNorm in place
  k_layernorm<<<NR, 256, 0, stream>>>(h, gamma, beta);
}

// Round 4
// 790.609 us; speedup vs baseline: 1.1091x; 1.1091x over previous
//
#include <hip/hip_runtime.h>

// ---------------------------------------------------------------------------
// TwoBranchFork: out = LN( concat(x@q(w_a)^T, x@q(w_b)^T) @ w_proj^T )
// Reassociated: W_eff = w_proj @ [q(w_a); q(w_b)]  (4096x4096), h = x @ W_eff^T
// Round 4: round-2 skeleton (best: 770us, MfmaUtil 43, conflicts 0) with ONE
// change: 16x16x32 -> 32x32x16 MFMA (+15% ceiling, half the issue slots).
// Phase/barrier/stage/vmcnt structure byte-identical to round 2:
//   P1[ds12(aTop+bC0) | stage A0(t+1) | bar | mfma Q1(top,c0) | bar]
//   P2[ds4(bC1)       | stage A1(t+1) | bar | mfma Q2(top,c1) | bar]
//   P3[ds8(aBot)      | stage B0(t+2) | bar | mfma Q3(bot,c1) | bar]
//   P4[               | stage B1(t+2) | bar | mfma Q4(bot,c0) | vmcnt(4) | bar]
// ---------------------------------------------------------------------------

typedef unsigned int u32;
typedef unsigned short u16;
typedef __bf16 bf16x8 __attribute__((ext_vector_type(8)));
typedef float f32x16 __attribute__((ext_vector_type(16)));
typedef u16 u16x8 __attribute__((ext_vector_type(8)));

#define AS1 __attribute__((address_space(1)))
#define AS3 __attribute__((address_space(3)))
#define FENCE() asm volatile("" ::: "memory")

__device__ __forceinline__ u16 f2bf(float f) {
  u32 u = __float_as_uint(f);
  u32 r = (u + 0x7fffu + ((u >> 16) & 1u)) >> 16;  // RNE
  return (u16)r;
}

// fp8 e4m3fn quantize-dequantize via HW cvt (OCP format + RNE on gfx950)
__device__ __forceinline__ float q_e4m3(float v) {
  int p = __builtin_amdgcn_cvt_pk_fp8_f32(v, v, 0, false);
  return __builtin_amdgcn_cvt_f32_fp8(p, 0);
}

__device__ __forceinline__ void gload16(const void* g, void* l) {
  __builtin_amdgcn_global_load_lds((const AS1 u32*)g, (AS3 u32*)l, 16, 0, 0);
}

// ---------------- elementwise f32 -> bf16 ----------------
__global__ __launch_bounds__(256) void k_f32_to_bf16(
    const float* __restrict__ in, u16* __restrict__ out, long n) {
  long i0 = ((long)blockIdx.x * 256 + threadIdx.x) * 8;
  long stride = (long)gridDim.x * 256 * 8;
  for (long i = i0; i < n; i += stride) {
    float4 a = *(const float4*)(in + i);
    float4 b = *(const float4*)(in + i + 4);
    u16x8 o;
    o[0] = f2bf(a.x); o[1] = f2bf(a.y); o[2] = f2bf(a.z); o[3] = f2bf(a.w);
    o[4] = f2bf(b.x); o[5] = f2bf(b.y); o[6] = f2bf(b.z); o[7] = f2bf(b.w);
    *(u16x8*)(out + i) = o;
  }
}

// ---------------- quantize (fp8 rt) + transpose into wqT ----------------
__global__ __launch_bounds__(256) void k_quant_transpose(
    const float* __restrict__ w, const float* __restrict__ s,
    u16* __restrict__ oT, int J, int Kd, int sCols, long oStride, int oColOff) {
  __shared__ u16 tile[64][72];
  int j0 = blockIdx.x * 64;
  int k0 = blockIdx.y * 64;
  float sc = s[(j0 >> 7) * sCols + (k0 >> 7)];
  int t = threadIdx.x;
  int row = t >> 2, seg = t & 3;
  const float4* src = (const float4*)(w + (long)(j0 + row) * Kd + k0 + seg * 16);
  u16* dst = &tile[row][seg * 16];
#pragma unroll
  for (int ii = 0; ii < 4; ++ii) {
    float4 v = src[ii];
    dst[ii * 4 + 0] = f2bf(q_e4m3(v.x / sc) * sc);
    dst[ii * 4 + 1] = f2bf(q_e4m3(v.y / sc) * sc);
    dst[ii * 4 + 2] = f2bf(q_e4m3(v.z / sc) * sc);
    dst[ii * 4 + 3] = f2bf(q_e4m3(v.w / sc) * sc);
  }
  __syncthreads();
  int r = t >> 2, cs = t & 3;
  u16* op = oT + (long)(k0 + r) * oStride + oColOff + j0 + cs * 16;
  u16x8 o0, o1;
#pragma unroll
  for (int ii = 0; ii < 8; ++ii) o0[ii] = tile[cs * 16 + ii][r];
#pragma unroll
  for (int ii = 0; ii < 8; ++ii) o1[ii] = tile[cs * 16 + 8 + ii][r];
  *(u16x8*)op = o0;
  *(u16x8*)(op + 8) = o1;
}

// ---------------- 256x256 8-phase bf16 bt-GEMM (32x32x16 MFMA) --------------
template <bool OUT_BF16>
__global__ __launch_bounds__(512, 2) void k_gemm8(
    const u16* __restrict__ A, const u16* __restrict__ B, void* __restrict__ Cv,
    int M, int N, int K) {
  __shared__ u16 sA[2][256 * 64];
  __shared__ u16 sB[2][256 * 64];

  const int tid = threadIdx.x;
  const int lane = tid & 63;
  const int wave = tid >> 6;
  const int wr = wave >> 2, wc = wave & 3;  // 2x4 wave grid, each 128x64 of C

  // T1: XCD-aware block swizzle (grid % 8 == 0 by construction)
  const int nwg = gridDim.x;
  const int wg = blockIdx.x;
  const int wgs = (wg & 7) * (nwg >> 3) + (wg >> 3);
  const int nbn = N >> 8;
  const int m0 = (wgs / nbn) << 8;
  const int n0 = (wgs % nbn) << 8;
  const int NT = K >> 6;

  const int l31 = lane & 31;
  const int khalf = lane >> 5;       // 0..1: 8-elem k-slot half for 32x32x16
  const int st_row = lane >> 3;      // staging: row within the 8-row stripe
  const int st_slot = lane & 7;
  const int st_src = ((st_slot ^ st_row) * 8);  // T2 inverse-swizzled source

  f32x16 acc[4][2] = {};

  auto stage = [&](const u16* __restrict__ G, int row0, u16* lds, int half,
                   int kt) {
#pragma unroll
    for (int r = 0; r < 2; ++r) {
      int row = half * 128 + r * 64 + wave * 8 + st_row;
      const u16* g = G + (long)(row0 + row) * K + kt * 64 + st_src;
      u16* l = lds + row * 64 + st_slot * 8;
      gload16(g, l);
    }
  };
  // T2 swizzled LDS fragment reads (32x32x16: A row=lane&31, k=khalf*8+j)
  auto ldA = [&](const u16* sa, int rblk, int ks) -> bf16x8 {
    int row = wr * 128 + rblk * 32 + l31;
    int slot = (ks * 2 + khalf) ^ (row & 7);
    return *(const bf16x8*)(sa + row * 64 + slot * 8);
  };
  auto ldB = [&](const u16* sb, int cblk, int ks) -> bf16x8 {
    int row = wc * 64 + cblk * 32 + l31;
    int slot = (ks * 2 + khalf) ^ (row & 7);
    return *(const bf16x8*)(sb + row * 64 + slot * 8);
  };

  // ---- prologue: tile0 fully + tile1 B halves; wait tile0, keep 4 in flight
  stage(A, m0, sA[0], 0, 0);
  stage(A, m0, sA[0], 1, 0);
  stage(B, n0, sB[0], 0, 0);
  stage(B, n0, sB[0], 1, 0);
  if (NT > 1) {
    stage(B, n0, sB[1], 0, 1);
    stage(B, n0, sB[1], 1, 1);
    asm volatile("s_waitcnt vmcnt(4)" ::: "memory");
  } else {
    asm volatile("s_waitcnt vmcnt(0)" ::: "memory");
  }
  __builtin_amdgcn_s_barrier();
  FENCE();

  for (int t = 0; t < NT; ++t) {
    const int p = t & 1;
    const u16* sa = sA[p];
    const u16* sb = sB[p];
    u16* saN = sA[p ^ 1];
    u16* sbC = sB[p];  // B(t+2) has same parity
    bf16x8 aT[2][4], aB[2][4], b0[4], b1[4];

    // ---- P1: ds x12 (aTop + bC0), stage A0(t+1), bar, mfma Q1(top,c0), bar
#pragma unroll
    for (int rb = 0; rb < 2; ++rb)
#pragma unroll
      for (int ks = 0; ks < 4; ++ks) aT[rb][ks] = ldA(sa, rb, ks);
#pragma unroll
    for (int ks = 0; ks < 4; ++ks) b0[ks] = ldB(sb, 0, ks);
    if (t + 1 < NT) stage(A, m0, saN, 0, t + 1);
    FENCE();
    __builtin_amdgcn_s_barrier();
    FENCE();
    __builtin_amdgcn_s_setprio(1);
#pragma unroll
    for (int rb = 0; rb < 2; ++rb)
#pragma unroll
      for (int ks = 0; ks < 4; ++ks)
        acc[rb][0] = __builtin_amdgcn_mfma_f32_32x32x16_bf16(
            aT[rb][ks], b0[ks], acc[rb][0], 0, 0, 0);
    __builtin_amdgcn_s_setprio(0);
    FENCE();
    __builtin_amdgcn_s_barrier();
    FENCE();

    // ---- P2: ds x4 (bC1), stage A1(t+1), bar, mfma Q2(top,c1), bar
#pragma unroll
    for (int ks = 0; ks < 4; ++ks) b1[ks] = ldB(sb, 1, ks);
    if (t + 1 < NT) stage(A, m0, saN, 1, t + 1);
    FENCE();
    __builtin_amdgcn_s_barrier();
    FENCE();
    __builtin_amdgcn_s_setprio(1);
#pragma unroll
    for (int rb = 0; rb < 2; ++rb)
#pragma unroll
      for (int ks = 0; ks < 4; ++ks)
        acc[rb][1] = __builtin_amdgcn_mfma_f32_32x32x16_bf16(
            aT[rb][ks], b1[ks], acc[rb][1], 0, 0, 0);
    __builtin_amdgcn_s_setprio(0);
    FENCE();
    __builtin_amdgcn_s_barrier();
    FENCE();

    // ---- P3: ds x8 (aBot), stage B0(t+2), bar, mfma Q3(bot,c1), bar
#pragma unroll
    for (int rb = 0; rb < 2; ++rb)
#pragma unroll
      for (int ks = 0; ks < 4; ++ks) aB[rb][ks] = ldA(sa, 2 + rb, ks);
    if (t + 2 < NT) stage(B, n0, sbC, 0, t + 2);
    FENCE();
    __builtin_amdgcn_s_barrier();
    FENCE();
    __builtin_amdgcn_s_setprio(1);
#pragma unroll
    for (int rb = 0; rb < 2; ++rb)
#pragma unroll
      for (int ks = 0; ks < 4; ++ks)
        acc[2 + rb][1] = __builtin_amdgcn_mfma_f32_32x32x16_bf16(
            aB[rb][ks], b1[ks], acc[2 + rb][1], 0, 0, 0);
    __builtin_amdgcn_s_setprio(0);
    FENCE();
    __builtin_amdgcn_s_barrier();
    FENCE();

    // ---- P4: stage B1(t+2), bar, mfma Q4(bot,c0), counted vmcnt, bar
    if (t + 2 < NT) stage(B, n0, sbC, 1, t + 2);
    FENCE();
    __builtin_amdgcn_s_barrier();
    FENCE();
    __builtin_amdgcn_s_setprio(1);
#pragma unroll
    for (int rb = 0; rb < 2; ++rb)
#pragma unroll
      for (int ks = 0; ks < 4; ++ks)
        acc[2 + rb][0] = __builtin_amdgcn_mfma_f32_32x32x16_bf16(
            aB[rb][ks], b0[ks], acc[2 + rb][0], 0, 0, 0);
    __builtin_amdgcn_s_setprio(0);
    FENCE();
    if (t + 2 < NT)
      asm volatile("s_waitcnt vmcnt(4)" ::: "memory");
    else
      asm volatile("s_waitcnt vmcnt(0)" ::: "memory");
    __builtin_amdgcn_s_barrier();
    FENCE();
  }

  // ---- epilogue: 32x32 C/D layout (m74/m101): col=lane&31,
  //      row=(reg&3)+8*(reg>>2)+4*(lane>>5)
  const int erow = khalf * 4;
  const int ecol = n0 + wc * 64 + l31;
#pragma unroll
  for (int rb = 0; rb < 4; ++rb) {
#pragma unroll
    for (int cb = 0; cb < 2; ++cb) {
#pragma unroll
      for (int reg = 0; reg < 16; ++reg) {
        int r = (reg & 3) + 8 * (reg >> 2) + erow;
        long off = (long)(m0 + wr * 128 + rb * 32 + r) * N + ecol + cb * 32;
        if (OUT_BF16)
          ((u16*)Cv)[off] = f2bf(acc[rb][cb][reg]);
        else
          ((float*)Cv)[off] = acc[rb][cb][reg];
      }
    }
  }
}

// ---------------- in-place LayerNorm over rows of 4096 ----------------
__global__ __launch_bounds__(256) void k_layernorm(
    float* __restrict__ h, const float* __restrict__ gamma,
    const float* __restrict__ beta) {
  const int H = 4096;
  float* p = h + (long)blockIdx.x * H;
  int t = threadIdx.x;
  float4 v[4];
  float sum = 0.f, sq = 0.f;
#pragma unroll
  for (int i = 0; i < 4; ++i) {
    v[i] = ((const float4*)p)[i * 256 + t];
    sum += v[i].x + v[i].y + v[i].z + v[i].w;
    sq += v[i].x * v[i].x + v[i].y * v[i].y + v[i].z * v[i].z + v[i].w * v[i].w;
  }
#pragma unroll
  for (int off = 32; off > 0; off >>= 1) {
    sum += __shfl_down(sum, off, 64);
    sq += __shfl_down(sq, off, 64);
  }
  __shared__ float ss[4], sg[4];
  if ((t & 63) == 0) { ss[t >> 6] = sum; sg[t >> 6] = sq; }
  __syncthreads();
  sum = ss[0] + ss[1] + ss[2] + ss[3];
  sq = sg[0] + sg[1] + sg[2] + sg[3];
  float mu = sum * (1.0f / H);
  float var = sq * (1.0f / H) - mu * mu;
  float rs = rsqrtf(var + 1e-5f);
#pragma unroll
  for (int i = 0; i < 4; ++i) {
    float4 g = ((const float4*)gamma)[i * 256 + t];
    float4 b = ((const float4*)beta)[i * 256 + t];
    float4 o;
    o.x = (v[i].x - mu) * rs * g.x + b.x;
    o.y = (v[i].y - mu) * rs * g.y + b.y;
    o.z = (v[i].z - mu) * rs * g.z + b.z;
    o.w = (v[i].w - mu) * rs * g.w + b.w;
    ((float4*)p)[i * 256 + t] = o;
  }
}

extern "C" void kernel_launch(void* const* d_in, const int* in_sizes, int n_in,
                              void* d_out, int out_size, void* d_ws,
                              size_t ws_size, hipStream_t stream) {
  const float* x      = (const float*)d_in[0];
  const float* w_a    = (const float*)d_in[1];
  const float* s_a    = (const float*)d_in[2];
  const float* w_b    = (const float*)d_in[3];
  const float* s_b    = (const float*)d_in[4];
  const float* w_proj = (const float*)d_in[5];
  const float* gamma  = (const float*)d_in[6];
  const float* beta   = (const float*)d_in[7];

  const int H = 4096, LO = 8192, SO = 2048, NR = 8192;
  const int KT = LO + SO;  // 10240

  char* ws = (char*)d_ws;
  u16* xb   = (u16*)(ws);                 // 64 MiB
  u16* wpb  = (u16*)(ws + 0x4000000L);    // 80 MiB
  u16* wqT  = (u16*)(ws + 0x9000000L);    // 80 MiB
  u16* weff = (u16*)(ws + 0xE000000L);    // 32 MiB
  float* h  = (float*)d_out;

  // 1. convert w_proj; quantize+transpose weights (GEMM1 operands first)
  k_f32_to_bf16<<<2048, 256, 0, stream>>>(w_proj, wpb, (long)H * KT);
  k_quant_transpose<<<dim3(LO / 64, H / 64), 256, 0, stream>>>(
      w_a, s_a, wqT, LO, H, H / 128, (long)KT, 0);
  k_quant_transpose<<<dim3(SO / 64, H / 64), 256, 0, stream>>>(
      w_b, s_b, wqT, SO, H, H / 128, (long)KT, LO);

  // 2. W_eff = w_proj @ Wq  -> bf16 [H][H]
  k_gemm8<true><<<(H / 256) * (H / 256), 512, 0, stream>>>(
      wpb, wqT, (void*)weff, H, H, KT);

  // 3. convert x (after GEMM1 so xb is LLC-hot for GEMM2)
  k_f32_to_bf16<<<2048, 256, 0, stream>>>(x, xb, (long)NR * H);

  // 4. h = x @ W_eff^T  -> fp32 into d_out
  k_gemm8<false><<<(NR / 256) * (H / 256), 512, 0, stream>>>(
      xb, weff, (void*)h, NR, H, H);

  // 5. LayerNorm in place
  k_layernorm<<<NR, 256, 0, stream>>>(h, gamma, beta);
}

// Round 5
// 771.347 us; speedup vs baseline: 1.1368x; 1.0250x over previous
//
#include <hip/hip_runtime.h>

// ---------------------------------------------------------------------------
// TwoBranchFork: out = LN( concat(x@q(w_a)^T, x@q(w_b)^T) @ w_proj^T )
// Reassociated: W_eff = w_proj @ [q(w_a); q(w_b)]  (4096x4096), h = x @ W_eff^T
// Round 5: round-2 skeleton (16x16x32, 0 conflicts) + balanced read-ahead:
//   P1[ds aT(8)      | stage A0(t+1) | bar | Q1: acc(mh0,n23)+=aT*b1r | bar]
//   P2[ds b0(4)      | stage A1(t+1) | bar | Q2: acc(mh0,n01)+=aT*b0  | bar]
//   P3[ds aB(8)      | stage B0(t+2) | bar | Q3: acc(mh1,n23)+=aB*b1r | bar]
//   P4[vmcnt(6) ds b1r<-B(t+1)(4) | stage B1(t+2) | bar |
//      Q4: acc(mh1,n01)+=aB*b0 | vmcnt(4) | bar]
// Ledger: b1r(t+1) read needs B(t+1) landed: outstanding at P4 = B(t+1)4 +
// A(t+1)4 + B0(t+2)2 -> vmcnt(6) (vmcnt(4) when B(t+2) unstaged). B(t+2)
// stage@P3 after last b(t) LDS read (b0@P2; b1@t-1 P4). Tail vmcnt(4) lands
// A(t+1). b1r overwrite@P4 after last use@P3. Prologue pre-reads b1r(0).
// ---------------------------------------------------------------------------

typedef unsigned int u32;
typedef unsigned short u16;
typedef __bf16 bf16x8 __attribute__((ext_vector_type(8)));
typedef float f32x4 __attribute__((ext_vector_type(4)));
typedef u16 u16x8 __attribute__((ext_vector_type(8)));

#define AS1 __attribute__((address_space(1)))
#define AS3 __attribute__((address_space(3)))
#define FENCE() asm volatile("" ::: "memory")

__device__ __forceinline__ u16 f2bf(float f) {
  u32 u = __float_as_uint(f);
  u32 r = (u + 0x7fffu + ((u >> 16) & 1u)) >> 16;  // RNE
  return (u16)r;
}

// fp8 e4m3fn quantize-dequantize via HW cvt (OCP format + RNE on gfx950)
__device__ __forceinline__ float q_e4m3(float v) {
  int p = __builtin_amdgcn_cvt_pk_fp8_f32(v, v, 0, false);
  return __builtin_amdgcn_cvt_f32_fp8(p, 0);
}

__device__ __forceinline__ void gload16(const void* g, void* l) {
  __builtin_amdgcn_global_load_lds((const AS1 u32*)g, (AS3 u32*)l, 16, 0, 0);
}

// ---------------- elementwise f32 -> bf16 ----------------
__global__ __launch_bounds__(256) void k_f32_to_bf16(
    const float* __restrict__ in, u16* __restrict__ out, long n) {
  long i0 = ((long)blockIdx.x * 256 + threadIdx.x) * 8;
  long stride = (long)gridDim.x * 256 * 8;
  for (long i = i0; i < n; i += stride) {
    float4 a = *(const float4*)(in + i);
    float4 b = *(const float4*)(in + i + 4);
    u16x8 o;
    o[0] = f2bf(a.x); o[1] = f2bf(a.y); o[2] = f2bf(a.z); o[3] = f2bf(a.w);
    o[4] = f2bf(b.x); o[5] = f2bf(b.y); o[6] = f2bf(b.z); o[7] = f2bf(b.w);
    *(u16x8*)(out + i) = o;
  }
}

// ---------------- quantize (fp8 rt) + transpose into wqT ----------------
__global__ __launch_bounds__(256) void k_quant_transpose(
    const float* __restrict__ w, const float* __restrict__ s,
    u16* __restrict__ oT, int J, int Kd, int sCols, long oStride, int oColOff) {
  __shared__ u16 tile[64][72];
  int j0 = blockIdx.x * 64;
  int k0 = blockIdx.y * 64;
  float sc = s[(j0 >> 7) * sCols + (k0 >> 7)];
  int t = threadIdx.x;
  int row = t >> 2, seg = t & 3;
  const float4* src = (const float4*)(w + (long)(j0 + row) * Kd + k0 + seg * 16);
  u16* dst = &tile[row][seg * 16];
#pragma unroll
  for (int ii = 0; ii < 4; ++ii) {
    float4 v = src[ii];
    dst[ii * 4 + 0] = f2bf(q_e4m3(v.x / sc) * sc);
    dst[ii * 4 + 1] = f2bf(q_e4m3(v.y / sc) * sc);
    dst[ii * 4 + 2] = f2bf(q_e4m3(v.z / sc) * sc);
    dst[ii * 4 + 3] = f2bf(q_e4m3(v.w / sc) * sc);
  }
  __syncthreads();
  int r = t >> 2, cs = t & 3;
  u16* op = oT + (long)(k0 + r) * oStride + oColOff + j0 + cs * 16;
  u16x8 o0, o1;
#pragma unroll
  for (int ii = 0; ii < 8; ++ii) o0[ii] = tile[cs * 16 + ii][r];
#pragma unroll
  for (int ii = 0; ii < 8; ++ii) o1[ii] = tile[cs * 16 + 8 + ii][r];
  *(u16x8*)op = o0;
  *(u16x8*)(op + 8) = o1;
}

// ---------------- 256x256 8-phase bf16 bt-GEMM: C = A[M,K] * B[N,K]^T -------
template <bool OUT_BF16>
__global__ __launch_bounds__(512, 2) void k_gemm8(
    const u16* __restrict__ A, const u16* __restrict__ B, void* __restrict__ Cv,
    int M, int N, int K) {
  __shared__ u16 sA[2][256 * 64];
  __shared__ u16 sB[2][256 * 64];

  const int tid = threadIdx.x;
  const int lane = tid & 63;
  const int wave = tid >> 6;
  const int wr = wave >> 2, wc = wave & 3;  // 2x4 wave grid, each 128x64 of C

  // T1: XCD-aware block swizzle (grid % 8 == 0 by construction)
  const int nwg = gridDim.x;
  const int wg = blockIdx.x;
  const int wgs = (wg & 7) * (nwg >> 3) + (wg >> 3);
  const int nbn = N >> 8;
  const int m0 = (wgs / nbn) << 8;
  const int n0 = (wgs % nbn) << 8;
  const int NT = K >> 6;

  const int lrow = lane & 15;
  const int kslot = lane >> 4;       // 0..3: 8-elem k-slot within 64-col row
  const int st_row = lane >> 3;      // staging: row within the 8-row stripe
  const int st_slot = lane & 7;
  const int st_src = ((st_slot ^ st_row) * 8);  // T2 inverse-swizzled source

  f32x4 acc[8][4] = {};

  auto stage = [&](const u16* __restrict__ G, int row0, u16* lds, int half,
                   int kt) {
#pragma unroll
    for (int r = 0; r < 2; ++r) {
      int row = half * 128 + r * 64 + wave * 8 + st_row;
      const u16* g = G + (long)(row0 + row) * K + kt * 64 + st_src;
      u16* l = lds + row * 64 + st_slot * 8;
      gload16(g, l);
    }
  };
  // T2 swizzled LDS fragment reads (2-way max bank aliasing = free)
  auto ldA = [&](const u16* sa, int mh, int m, int ks) -> bf16x8 {
    int row = wr * 128 + mh * 64 + m * 16 + lrow;
    int slot = (ks * 4 + kslot) ^ (row & 7);
    return *(const bf16x8*)(sa + row * 64 + slot * 8);
  };
  auto ldB = [&](const u16* sb, int n, int ks) -> bf16x8 {
    int row = wc * 64 + n * 16 + lrow;
    int slot = (ks * 4 + kslot) ^ (row & 7);
    return *(const bf16x8*)(sb + row * 64 + slot * 8);
  };

  // ---- prologue: tile0 fully + tile1 B halves; wait tile0; pre-read b1r(0)
  stage(A, m0, sA[0], 0, 0);
  stage(A, m0, sA[0], 1, 0);
  stage(B, n0, sB[0], 0, 0);
  stage(B, n0, sB[0], 1, 0);
  if (NT > 1) {
    stage(B, n0, sB[1], 0, 1);
    stage(B, n0, sB[1], 1, 1);
    asm volatile("s_waitcnt vmcnt(4)" ::: "memory");
  } else {
    asm volatile("s_waitcnt vmcnt(0)" ::: "memory");
  }
  __builtin_amdgcn_s_barrier();
  FENCE();

  bf16x8 b1r[2][2];  // loop-carried: B cols n{2,3} of tile t
#pragma unroll
  for (int n = 0; n < 2; ++n)
#pragma unroll
    for (int ks = 0; ks < 2; ++ks) b1r[n][ks] = ldB(sB[0], n + 2, ks);

  for (int t = 0; t < NT; ++t) {
    const int p = t & 1;
    const u16* sa = sA[p];
    const u16* sb = sB[p];
    u16* saN = sA[p ^ 1];
    const u16* sbN = sB[p ^ 1];  // B(t+1), resident
    u16* sbC = sB[p];            // B(t+2) dest (same parity)
    bf16x8 aT[4][2], aB[4][2], b0r[2][2];

    // ---- P1: ds aT(8) | stage A0(t+1) | bar | Q1: acc(mh0,n23) += aT*b1r
#pragma unroll
    for (int m = 0; m < 4; ++m)
#pragma unroll
      for (int ks = 0; ks < 2; ++ks) aT[m][ks] = ldA(sa, 0, m, ks);
    if (t + 1 < NT) stage(A, m0, saN, 0, t + 1);
    FENCE();
    __builtin_amdgcn_s_barrier();
    FENCE();
    __builtin_amdgcn_s_setprio(1);
#pragma unroll
    for (int m = 0; m < 4; ++m)
#pragma unroll
      for (int n = 0; n < 2; ++n)
#pragma unroll
        for (int ks = 0; ks < 2; ++ks)
          acc[m][n + 2] = __builtin_amdgcn_mfma_f32_16x16x32_bf16(
              aT[m][ks], b1r[n][ks], acc[m][n + 2], 0, 0, 0);
    __builtin_amdgcn_s_setprio(0);
    FENCE();
    __builtin_amdgcn_s_barrier();
    FENCE();

    // ---- P2: ds b0(4) | stage A1(t+1) | bar | Q2: acc(mh0,n01) += aT*b0
#pragma unroll
    for (int n = 0; n < 2; ++n)
#pragma unroll
      for (int ks = 0; ks < 2; ++ks) b0r[n][ks] = ldB(sb, n, ks);
    if (t + 1 < NT) stage(A, m0, saN, 1, t + 1);
    FENCE();
    __builtin_amdgcn_s_barrier();
    FENCE();
    __builtin_amdgcn_s_setprio(1);
#pragma unroll
    for (int m = 0; m < 4; ++m)
#pragma unroll
      for (int n = 0; n < 2; ++n)
#pragma unroll
        for (int ks = 0; ks < 2; ++ks)
          acc[m][n] = __builtin_amdgcn_mfma_f32_16x16x32_bf16(
              aT[m][ks], b0r[n][ks], acc[m][n], 0, 0, 0);
    __builtin_amdgcn_s_setprio(0);
    FENCE();
    __builtin_amdgcn_s_barrier();
    FENCE();

    // ---- P3: ds aB(8) | stage B0(t+2) | bar | Q3: acc(mh1,n23) += aB*b1r
#pragma unroll
    for (int m = 0; m < 4; ++m)
#pragma unroll
      for (int ks = 0; ks < 2; ++ks) aB[m][ks] = ldA(sa, 1, m, ks);
    if (t + 2 < NT) stage(B, n0, sbC, 0, t + 2);
    FENCE();
    __builtin_amdgcn_s_barrier();
    FENCE();
    __builtin_amdgcn_s_setprio(1);
#pragma unroll
    for (int m = 0; m < 4; ++m)
#pragma unroll
      for (int n = 0; n < 2; ++n)
#pragma unroll
        for (int ks = 0; ks < 2; ++ks)
          acc[4 + m][n + 2] = __builtin_amdgcn_mfma_f32_16x16x32_bf16(
              aB[m][ks], b1r[n][ks], acc[4 + m][n + 2], 0, 0, 0);
    __builtin_amdgcn_s_setprio(0);
    FENCE();
    __builtin_amdgcn_s_barrier();
    FENCE();

    // ---- P4: vmcnt(6|4); ds b1r<-B(t+1); stage B1(t+2) | bar |
    //          Q4: acc(mh1,n01) += aB*b0 | vmcnt(4|0) | bar
    if (t + 1 < NT) {
      if (t + 2 < NT)
        asm volatile("s_waitcnt vmcnt(6)" ::: "memory");
      else
        asm volatile("s_waitcnt vmcnt(4)" ::: "memory");
      FENCE();
#pragma unroll
      for (int n = 0; n < 2; ++n)
#pragma unroll
        for (int ks = 0; ks < 2; ++ks) b1r[n][ks] = ldB(sbN, n + 2, ks);
    }
    if (t + 2 < NT) stage(B, n0, sbC, 1, t + 2);
    FENCE();
    __builtin_amdgcn_s_barrier();
    FENCE();
    __builtin_amdgcn_s_setprio(1);
#pragma unroll
    for (int m = 0; m < 4; ++m)
#pragma unroll
      for (int n = 0; n < 2; ++n)
#pragma unroll
        for (int ks = 0; ks < 2; ++ks)
          acc[4 + m][n] = __builtin_amdgcn_mfma_f32_16x16x32_bf16(
              aB[m][ks], b0r[n][ks], acc[4 + m][n], 0, 0, 0);
    __builtin_amdgcn_s_setprio(0);
    FENCE();
    if (t + 2 < NT)
      asm volatile("s_waitcnt vmcnt(4)" ::: "memory");
    else
      asm volatile("s_waitcnt vmcnt(0)" ::: "memory");
    __builtin_amdgcn_s_barrier();
    FENCE();
  }

  // ---- epilogue: C/D layout col=lane&15, row=(lane>>4)*4+reg (m89-verified)
  const int rb = m0 + wr * 128 + (lane >> 4) * 4;
  const int cb = n0 + wc * 64 + lrow;
#pragma unroll
  for (int mf = 0; mf < 8; ++mf) {
#pragma unroll
    for (int r = 0; r < 4; ++r) {
      const long rowoff = (long)(rb + mf * 16 + r) * N + cb;
#pragma unroll
      for (int n = 0; n < 4; ++n) {
        if (OUT_BF16)
          ((u16*)Cv)[rowoff + n * 16] = f2bf(acc[mf][n][r]);
        else
          ((float*)Cv)[rowoff + n * 16] = acc[mf][n][r];
      }
    }
  }
}

// ---------------- in-place LayerNorm over rows of 4096 ----------------
__global__ __launch_bounds__(256) void k_layernorm(
    float* __restrict__ h, const float* __restrict__ gamma,
    const float* __restrict__ beta) {
  const int H = 4096;
  float* p = h + (long)blockIdx.x * H;
  int t = threadIdx.x;
  float4 v[4];
  float sum = 0.f, sq = 0.f;
#pragma unroll
  for (int i = 0; i < 4; ++i) {
    v[i] = ((const float4*)p)[i * 256 + t];
    sum += v[i].x + v[i].y + v[i].z + v[i].w;
    sq += v[i].x * v[i].x + v[i].y * v[i].y + v[i].z * v[i].z + v[i].w * v[i].w;
  }
#pragma unroll
  for (int off = 32; off > 0; off >>= 1) {
    sum += __shfl_down(sum, off, 64);
    sq += __shfl_down(sq, off, 64);
  }
  __shared__ float ss[4], sg[4];
  if ((t & 63) == 0) { ss[t >> 6] = sum; sg[t >> 6] = sq; }
  __syncthreads();
  sum = ss[0] + ss[1] + ss[2] + ss[3];
  sq = sg[0] + sg[1] + sg[2] + sg[3];
  float mu = sum * (1.0f / H);
  float var = sq * (1.0f / H) - mu * mu;
  float rs = rsqrtf(var + 1e-5f);
#pragma unroll
  for (int i = 0; i < 4; ++i) {
    float4 g = ((const float4*)gamma)[i * 256 + t];
    float4 b = ((const float4*)beta)[i * 256 + t];
    float4 o;
    o.x = (v[i].x - mu) * rs * g.x + b.x;
    o.y = (v[i].y - mu) * rs * g.y + b.y;
    o.z = (v[i].z - mu) * rs * g.z + b.z;
    o.w = (v[i].w - mu) * rs * g.w + b.w;
    ((float4*)p)[i * 256 + t] = o;
  }
}

extern "C" void kernel_launch(void* const* d_in, const int* in_sizes, int n_in,
                              void* d_out, int out_size, void* d_ws,
                              size_t ws_size, hipStream_t stream) {
  const float* x      = (const float*)d_in[0];
  const float* w_a    = (const float*)d_in[1];
  const float* s_a    = (const float*)d_in[2];
  const float* w_b    = (const float*)d_in[3];
  const float* s_b    = (const float*)d_in[4];
  const float* w_proj = (const float*)d_in[5];
  const float* gamma  = (const float*)d_in[6];
  const float* beta   = (const float*)d_in[7];

  const int H = 4096, LO = 8192, SO = 2048, NR = 8192;
  const int KT = LO + SO;  // 10240

  char* ws = (char*)d_ws;
  u16* xb   = (u16*)(ws);                 // 64 MiB
  u16* wpb  = (u16*)(ws + 0x4000000L);    // 80 MiB
  u16* wqT  = (u16*)(ws + 0x9000000L);    // 80 MiB
  u16* weff = (u16*)(ws + 0xE000000L);    // 32 MiB
  float* h  = (float*)d_out;

  // 1. convert w_proj; quantize+transpose weights (GEMM1 operands first)
  k_f32_to_bf16<<<2048, 256, 0, stream>>>(w_proj, wpb, (long)H * KT);
  k_quant_transpose<<<dim3(LO / 64, H / 64), 256, 0, stream>>>(
      w_a, s_a, wqT, LO, H, H / 128, (long)KT, 0);
  k_quant_transpose<<<dim3(SO / 64, H / 64), 256, 0, stream>>>(
      w_b, s_b, wqT, SO, H, H / 128, (long)KT, LO);

  // 2. W_eff = w_proj @ Wq  -> bf16 [H][H]
  k_gemm8<true><<<(H / 256) * (H / 256), 512, 0, stream>>>(
      wpb, wqT, (void*)weff, H, H, KT);

  // 3. convert x (after GEMM1 so xb is LLC-hot for GEMM2)
  k_f32_to_bf16<<<2048, 256, 0, stream>>>(x, xb, (long)NR * H);

  // 4. h = x @ W_eff^T  -> fp32 into d_out
  k_gemm8<false><<<(NR / 256) * (H / 256), 512, 0, stream>>>(
      xb, weff, (void*)h, NR, H, H);

  // 5. LayerNorm in place
  k_layernorm<<<NR, 256, 0, stream>>>(h, gamma, beta);
}